// Round 2
// baseline (435.601 us; speedup 1.0000x reference)
//
#include <hip/hip_runtime.h>

typedef _Float16 h16_t;
typedef _Float16 half8 __attribute__((ext_vector_type(8)));
typedef _Float16 half4v __attribute__((ext_vector_type(4)));
typedef float f32x4 __attribute__((ext_vector_type(4)));

#define SEQ 2048
#define DM 2048
#define NHEAD 16
#define HDIM 128
#define QKVW 6144

// ---------------- fp32 -> (hi,lo) fp16 split ----------------
__global__ void cvt_split(const float* __restrict__ src, h16_t* __restrict__ hi,
                          h16_t* __restrict__ lo, int n4) {
  int i = blockIdx.x * blockDim.x + threadIdx.x;
  if (i < n4) {
    float4 v = reinterpret_cast<const float4*>(src)[i];
    half4v h, l;
    float x;
    x = v.x; h[0] = (h16_t)x; l[0] = (h16_t)(x - (float)h[0]);
    x = v.y; h[1] = (h16_t)x; l[1] = (h16_t)(x - (float)h[1]);
    x = v.z; h[2] = (h16_t)x; l[2] = (h16_t)(x - (float)h[2]);
    x = v.w; h[3] = (h16_t)x; l[3] = (h16_t)(x - (float)h[3]);
    reinterpret_cast<half4v*>(hi)[i] = h;
    reinterpret_cast<half4v*>(lo)[i] = l;
  }
}

// ---------------- fp32 W[K][N] -> fp16 Wt[N][K] hi (+ lo for n < Nlo) -------
__global__ void transpose_split(const float* __restrict__ W, h16_t* __restrict__ Wt_hi,
                                h16_t* __restrict__ Wt_lo, int K, int N, int Nlo) {
  __shared__ float tile[32][33];
  int n0 = blockIdx.x * 32, k0 = blockIdx.y * 32;
  int tx = threadIdx.x, ty = threadIdx.y;  // 32 x 8
#pragma unroll
  for (int j = 0; j < 4; ++j)
    tile[ty + 8 * j][tx] = W[(size_t)(k0 + ty + 8 * j) * N + n0 + tx];
  __syncthreads();
  bool do_lo = (Wt_lo != nullptr) && (n0 < Nlo);
#pragma unroll
  for (int j = 0; j < 4; ++j) {
    float v = tile[tx][ty + 8 * j];
    h16_t hv = (h16_t)v;
    size_t off = (size_t)(n0 + ty + 8 * j) * K + k0 + tx;
    Wt_hi[off] = hv;
    if (do_lo) Wt_lo[off] = (h16_t)(v - (float)hv);
  }
}

// ---------------- GEMM: C[M][N] = A[M][K] * Bt[N][K]^T + bias ----------------
// 128x128 tile, BK=32, 4 waves (2x2), each wave 64x64 = 4x4 16x16x32 frags.
// SPLIT: 3-product Markidis (Ahi*Bhi + Ahi*Blo + Alo*Bhi).
// OUT: 0 = fp16 hi only, 1 = fp16 hi + lo, 2 = fp32.
template <int SPLIT, int OUT>
__global__ __launch_bounds__(256) void gemm_f16(
    const h16_t* __restrict__ Ahi, const h16_t* __restrict__ Alo,
    const h16_t* __restrict__ Bhi, const h16_t* __restrict__ Blo,
    const float* __restrict__ bias, void* __restrict__ Cout,
    h16_t* __restrict__ Clo, int ldc, int K, int ldlo) {
  extern __shared__ __align__(16) char smem[];
  h16_t* As_hi = (h16_t*)smem;
  h16_t* Bs_hi = (h16_t*)(smem + 8192);
  h16_t* As_lo = (h16_t*)(smem + 16384);
  h16_t* Bs_lo = (h16_t*)(smem + 24576);

  const int tid = threadIdx.x;
  const int w = tid >> 6, lane = tid & 63, c = lane & 15, g = lane >> 4;
  const int brow = blockIdx.y * 128, bcol = blockIdx.x * 128;
  const int wr = (w >> 1) * 64, wc = (w & 1) * 64;

  f32x4 acc[4][4] = {};

  half8 pah[2], pbh[2], pal[2], pbl[2];
#pragma unroll
  for (int p = 0; p < 2; ++p) {
    int bl = p * 256 + tid, row = bl >> 2, c8 = bl & 3;
    pah[p] = *reinterpret_cast<const half8*>(Ahi + (size_t)(brow + row) * K + c8 * 8);
    pbh[p] = *reinterpret_cast<const half8*>(Bhi + (size_t)(bcol + row) * K + c8 * 8);
    if (SPLIT) {
      pal[p] = *reinterpret_cast<const half8*>(Alo + (size_t)(brow + row) * K + c8 * 8);
      pbl[p] = *reinterpret_cast<const half8*>(Blo + (size_t)(bcol + row) * K + c8 * 8);
    }
  }

  for (int k0 = 0; k0 < K; k0 += 32) {
#pragma unroll
    for (int p = 0; p < 2; ++p) {
      int bl = p * 256 + tid, row = bl >> 2, c8 = bl & 3;
      int sw = c8 ^ ((row >> 1) & 3);
      *reinterpret_cast<half8*>((char*)As_hi + row * 64 + sw * 16) = pah[p];
      *reinterpret_cast<half8*>((char*)Bs_hi + row * 64 + sw * 16) = pbh[p];
      if (SPLIT) {
        *reinterpret_cast<half8*>((char*)As_lo + row * 64 + sw * 16) = pal[p];
        *reinterpret_cast<half8*>((char*)Bs_lo + row * 64 + sw * 16) = pbl[p];
      }
    }
    __syncthreads();
    if (k0 + 32 < K) {
#pragma unroll
      for (int p = 0; p < 2; ++p) {
        int bl = p * 256 + tid, row = bl >> 2, c8 = bl & 3;
        pah[p] = *reinterpret_cast<const half8*>(Ahi + (size_t)(brow + row) * K + (k0 + 32) + c8 * 8);
        pbh[p] = *reinterpret_cast<const half8*>(Bhi + (size_t)(bcol + row) * K + (k0 + 32) + c8 * 8);
        if (SPLIT) {
          pal[p] = *reinterpret_cast<const half8*>(Alo + (size_t)(brow + row) * K + (k0 + 32) + c8 * 8);
          pbl[p] = *reinterpret_cast<const half8*>(Blo + (size_t)(bcol + row) * K + (k0 + 32) + c8 * 8);
        }
      }
    }
    half8 afh[4], bfh[4], afl[4], bfl[4];
#pragma unroll
    for (int f = 0; f < 4; ++f) {
      int rowa = wr + f * 16 + c;
      int offa = rowa * 64 + ((g ^ ((rowa >> 1) & 3)) * 16);
      int rowb = wc + f * 16 + c;
      int offb = rowb * 64 + ((g ^ ((rowb >> 1) & 3)) * 16);
      afh[f] = *reinterpret_cast<const half8*>((char*)As_hi + offa);
      bfh[f] = *reinterpret_cast<const half8*>((char*)Bs_hi + offb);
      if (SPLIT) {
        afl[f] = *reinterpret_cast<const half8*>((char*)As_lo + offa);
        bfl[f] = *reinterpret_cast<const half8*>((char*)Bs_lo + offb);
      }
    }
#pragma unroll
    for (int fm = 0; fm < 4; ++fm)
#pragma unroll
      for (int fn = 0; fn < 4; ++fn) {
        acc[fm][fn] = __builtin_amdgcn_mfma_f32_16x16x32_f16(afh[fm], bfh[fn], acc[fm][fn], 0, 0, 0);
        if (SPLIT) {
          acc[fm][fn] = __builtin_amdgcn_mfma_f32_16x16x32_f16(afh[fm], bfl[fn], acc[fm][fn], 0, 0, 0);
          acc[fm][fn] = __builtin_amdgcn_mfma_f32_16x16x32_f16(afl[fm], bfh[fn], acc[fm][fn], 0, 0, 0);
        }
      }
    __syncthreads();
  }

#pragma unroll
  for (int fm = 0; fm < 4; ++fm)
#pragma unroll
    for (int fn = 0; fn < 4; ++fn) {
      int col = bcol + wc + fn * 16 + c;
      float bv = bias[col];
#pragma unroll
      for (int r = 0; r < 4; ++r) {
        int row = brow + wr + fm * 16 + 4 * g + r;
        float v = acc[fm][fn][r] + bv;
        if (OUT == 2) {
          ((float*)Cout)[(size_t)row * ldc + col] = v;
        } else {
          h16_t hv = (h16_t)v;
          ((h16_t*)Cout)[(size_t)row * ldc + col] = hv;
          if (OUT == 1) Clo[(size_t)row * ldlo + col] = (h16_t)(v - (float)hv);
        }
      }
    }
}

// ---------------- cos/sin table [SEQ][64] fp32 ----------------
__global__ void ctab_kernel(float2* __restrict__ tab) {
  int idx = blockIdx.x * blockDim.x + threadIdx.x;  // 2048*64
  int s = idx >> 6, i = idx & 63;
  float freq = 1.0f / powf(10000.0f, (float)(2 * i) / 128.0f);
  float ang = (float)s * freq;  // same op order as reference outer(t, freqs)
  float sn, cs;
  sincosf(ang, &sn, &cs);
  tab[idx] = make_float2(cs, sn);
}

// ---------------- RoPE (interleaved pairs), in-place on split q,k ----------
__global__ void rope_kernel(h16_t* __restrict__ hi, h16_t* __restrict__ lo,
                            const float2* __restrict__ tab) {
  int idx = blockIdx.x * blockDim.x + threadIdx.x;  // 2048*2*16*64
  int i = idx & 63;
  int hh = (idx >> 6) & 15;
  int part = (idx >> 10) & 1;
  int s = idx >> 11;
  float2 cc = tab[s * 64 + i];
  size_t offh = (size_t)s * QKVW + part * 2048 + hh * 128 + 2 * i;
  size_t offl = (size_t)s * 4096 + part * 2048 + hh * 128 + 2 * i;
  float x0 = (float)hi[offh] + (float)lo[offl];
  float x1 = (float)hi[offh + 1] + (float)lo[offl + 1];
  float y0 = x0 * cc.x - x1 * cc.y;
  float y1 = x0 * cc.y + x1 * cc.x;
  h16_t h0 = (h16_t)y0, h1 = (h16_t)y1;
  hi[offh] = h0;     lo[offl] = (h16_t)(y0 - (float)h0);
  hi[offh + 1] = h1; lo[offl + 1] = (h16_t)(y1 - (float)h1);
}

// ---------------- causal flash attention (split q,k logits) ----------------
// grid (32 qblocks, 16 heads), 256 thr. QB=64 (16 q-rows/wave), KB=64.
// S^T = mfma(K, Q): lane holds q = lane&15, keys 16*fm + 4*g + r.
__global__ __launch_bounds__(256) void attn_kernel(const h16_t* __restrict__ qhi,
                                                   const h16_t* __restrict__ qlo,
                                                   h16_t* __restrict__ ctx) {
  __shared__ __align__(16) h16_t Kh[64 * 128];
  __shared__ __align__(16) h16_t Kl[64 * 128];
  __shared__ __align__(16) h16_t Vlds[64 * 128];
  const int tid = threadIdx.x, w = tid >> 6, lane = tid & 63, c = lane & 15, g = lane >> 4;
  const int h = blockIdx.y, qb = blockIdx.x;
  const int q0 = qb * 64, qw = q0 + w * 16;
  const h16_t* Kph = qhi + 2048 + h * HDIM;
  const h16_t* Kpl = qlo + 2048 + h * HDIM;
  const h16_t* Vp = qhi + 4096 + h * HDIM;

  half8 qfh[4], qfl[4];
#pragma unroll
  for (int kc = 0; kc < 4; ++kc) {
    qfh[kc] = *reinterpret_cast<const half8*>(qhi + (size_t)(qw + c) * QKVW + h * HDIM + kc * 32 + g * 8);
    qfl[kc] = *reinterpret_cast<const half8*>(qlo + (size_t)(qw + c) * 4096 + h * HDIM + kc * 32 + g * 8);
  }

  f32x4 oacc[8] = {};
  float m_run = -3.0e38f, s_run = 0.f;
  const float L2E = 1.4426950408889634f;

  const int ntiles = qb + 1;
  for (int t = 0; t < ntiles; ++t) {
    const int k0 = t * 64;
    __syncthreads();
    // stage K hi/lo, XOR-swizzled 16B blocks within each 256B row
#pragma unroll
    for (int p = 0; p < 4; ++p) {
      int bl = p * 256 + tid, row = bl >> 4, c16 = bl & 15;
      half8 vh = *reinterpret_cast<const half8*>(Kph + (size_t)(k0 + row) * QKVW + c16 * 8);
      half8 vl = *reinterpret_cast<const half8*>(Kpl + (size_t)(k0 + row) * 4096 + c16 * 8);
      int so = row * 256 + ((c16 ^ (row & 7)) * 16);
      *reinterpret_cast<half8*>((char*)Kh + so) = vh;
      *reinterpret_cast<half8*>((char*)Kl + so) = vl;
    }
    // stage V into slot-permuted layout: half idx = i + 8*(d&15) + 128*((key>>2)&3)
    //   + 512*(key>>5) + 1024*(d>>4), i = 4*((key>>4)&1) + (key&3)
#pragma unroll
    for (int p = 0; p < 4; ++p) {
      int bl = p * 256 + tid, key = bl >> 4, d0 = (bl & 15) * 8;
      half8 v = *reinterpret_cast<const half8*>(Vp + (size_t)(k0 + key) * QKVW + d0);
      int K1 = key >> 4, gg = (key >> 2) & 3, r = key & 3;
      int base = (4 * (K1 & 1) + r) + 128 * gg + 512 * (K1 >> 1);
#pragma unroll
      for (int j = 0; j < 8; ++j) {
        int d = d0 + j;
        Vlds[base + 8 * (d & 15) + 1024 * (d >> 4)] = v[j];
      }
    }
    __syncthreads();

    // S^T, 3-product split
    f32x4 st[4] = {};
#pragma unroll
    for (int kc = 0; kc < 4; ++kc)
#pragma unroll
      for (int fm = 0; fm < 4; ++fm) {
        int row = fm * 16 + c;
        int so = row * 256 + (((4 * kc + g) ^ (row & 7)) * 16);
        half8 kfh = *reinterpret_cast<const half8*>((char*)Kh + so);
        half8 kfl = *reinterpret_cast<const half8*>((char*)Kl + so);
        st[fm] = __builtin_amdgcn_mfma_f32_16x16x32_f16(kfh, qfh[kc], st[fm], 0, 0, 0);
        st[fm] = __builtin_amdgcn_mfma_f32_16x16x32_f16(kfh, qfl[kc], st[fm], 0, 0, 0);
        st[fm] = __builtin_amdgcn_mfma_f32_16x16x32_f16(kfl, qfh[kc], st[fm], 0, 0, 0);
      }

    // scale + causal mask + online softmax
    float p_[4][4];
    float tmax = -3.0e38f;
    const int qg = qw + c;
#pragma unroll
    for (int fm = 0; fm < 4; ++fm)
#pragma unroll
      for (int r = 0; r < 4; ++r) {
        float sf = st[fm][r] * 11.31370850f;  // * sqrt(128), per reference
        int key = k0 + fm * 16 + 4 * g + r;
        sf = (key > qg) ? -3.0e38f : sf;
        p_[fm][r] = sf;
        tmax = fmaxf(tmax, sf);
      }
    tmax = fmaxf(tmax, __shfl_xor(tmax, 16));
    tmax = fmaxf(tmax, __shfl_xor(tmax, 32));
    float m_new = fmaxf(m_run, tmax);
    float alpha = exp2f((m_run - m_new) * L2E);
    float rs = 0.f;
#pragma unroll
    for (int fm = 0; fm < 4; ++fm)
#pragma unroll
      for (int r = 0; r < 4; ++r) {
        float e = exp2f((p_[fm][r] - m_new) * L2E);
        p_[fm][r] = e;
        rs += e;
      }
    rs += __shfl_xor(rs, 16);
    rs += __shfl_xor(rs, 32);
    s_run = s_run * alpha + rs;
    m_run = m_new;

    float ar[4];
#pragma unroll
    for (int r = 0; r < 4; ++r) ar[r] = __shfl(alpha, 4 * g + r);
#pragma unroll
    for (int tt = 0; tt < 8; ++tt)
#pragma unroll
      for (int r = 0; r < 4; ++r) oacc[tt][r] *= ar[r];

    // pack P fragments (pure per-lane thanks to slot-permuted V layout)
    half8 ap[2];
#pragma unroll
    for (int kc = 0; kc < 2; ++kc)
#pragma unroll
      for (int i = 0; i < 8; ++i) ap[kc][i] = (h16_t)p_[2 * kc + (i >> 2)][i & 3];

    // PV
#pragma unroll
    for (int tt = 0; tt < 8; ++tt)
#pragma unroll
      for (int kc = 0; kc < 2; ++kc) {
        half8 vf = *reinterpret_cast<const half8*>(
            (const char*)Vlds + 16 * c + 256 * g + 1024 * kc + 2048 * tt);
        oacc[tt] = __builtin_amdgcn_mfma_f32_16x16x32_f16(ap[kc], vf, oacc[tt], 0, 0, 0);
      }
  }

  float sr[4];
#pragma unroll
  for (int r = 0; r < 4; ++r) sr[r] = __shfl(s_run, 4 * g + r);
#pragma unroll
  for (int tt = 0; tt < 8; ++tt)
#pragma unroll
    for (int r = 0; r < 4; ++r) {
      float v = oacc[tt][r] / sr[r];
      ctx[(size_t)(qw + 4 * g + r) * DM + h * HDIM + tt * 16 + c] = (h16_t)v;
    }
}

extern "C" void kernel_launch(void* const* d_in, const int* in_sizes, int n_in,
                              void* d_out, int out_size, void* d_ws, size_t ws_size,
                              hipStream_t stream) {
  const float* hs   = (const float*)d_in[0];
  const float* wqkv = (const float*)d_in[1];
  const float* bqkv = (const float*)d_in[2];
  const float* wo   = (const float*)d_in[3];
  const float* bo   = (const float*)d_in[4];
  float* out = (float*)d_out;

  char* ws = (char*)d_ws;
  const size_t MB = 1u << 20;
  h16_t* h_hi    = (h16_t*)(ws + 0 * MB);    // 8 MB  (reused as ctx16 later)
  h16_t* h_lo    = (h16_t*)(ws + 8 * MB);    // 8 MB
  h16_t* qkvT_hi = (h16_t*)(ws + 16 * MB);   // 24 MB [6144][2048]
  h16_t* qkvT_lo = (h16_t*)(ws + 40 * MB);   // 16 MB [4096][2048]
  h16_t* woT     = (h16_t*)(ws + 56 * MB);   // 8 MB  [2048][2048]
  h16_t* qkv_hi  = (h16_t*)(ws + 64 * MB);   // 24 MB [2048][6144]
  h16_t* qkv_lo  = (h16_t*)(ws + 88 * MB);   // 16 MB [2048][4096]
  float2* ctab   = (float2*)(ws + 104 * MB); // 1 MB  [2048][64]
  h16_t* ctx16   = h_hi;

  cvt_split<<<(SEQ * DM / 4 + 255) / 256, 256, 0, stream>>>(hs, h_hi, h_lo, SEQ * DM / 4);
  transpose_split<<<dim3(QKVW / 32, DM / 32), dim3(32, 8), 0, stream>>>(
      wqkv, qkvT_hi, qkvT_lo, DM, QKVW, 4096);
  transpose_split<<<dim3(DM / 32, DM / 32), dim3(32, 8), 0, stream>>>(
      wo, woT, nullptr, DM, DM, 0);
  ctab_kernel<<<(SEQ * 64) / 256, 256, 0, stream>>>(ctab);

  // q,k columns: split 3-product GEMM, writes hi+lo
  gemm_f16<1, 1><<<dim3(32, 16), 256, 32768, stream>>>(
      h_hi, h_lo, qkvT_hi, qkvT_lo, bqkv, qkv_hi, qkv_lo, QKVW, DM, 4096);
  // v columns: plain GEMM, hi only
  gemm_f16<0, 0><<<dim3(16, 16), 256, 16384, stream>>>(
      h_hi, nullptr, qkvT_hi + (size_t)4096 * DM, nullptr, bqkv + 4096,
      qkv_hi + 4096, nullptr, QKVW, DM, 0);

  rope_kernel<<<(SEQ * 2 * NHEAD * 64) / 256, 256, 0, stream>>>(qkv_hi, qkv_lo, ctab);

  attn_kernel<<<dim3(SEQ / 64, NHEAD), 256, 0, stream>>>(qkv_hi, qkv_lo, ctx16);

  gemm_f16<0, 2><<<dim3(DM / 128, SEQ / 128), 256, 16384, stream>>>(
      ctx16, nullptr, woT, nullptr, bo, out, nullptr, DM, DM, 0);
}

// Round 3
// 317.805 us; speedup vs baseline: 1.3707x; 1.3707x over previous
//
#include <hip/hip_runtime.h>

typedef _Float16 h16_t;
typedef _Float16 half8 __attribute__((ext_vector_type(8)));
typedef _Float16 half4v __attribute__((ext_vector_type(4)));
typedef float f32x4 __attribute__((ext_vector_type(4)));

#define SEQ 2048
#define DM 2048
#define NHEAD 16
#define HDIM 128
#define QKVW 6144

#define GLOAD_LDS(g, l)                                                   \
  __builtin_amdgcn_global_load_lds(                                       \
      (const __attribute__((address_space(1))) void*)(g),                 \
      (__attribute__((address_space(3))) void*)(l), 16, 0, 0)

#define VMCNT0 asm volatile("s_waitcnt vmcnt(0)" ::: "memory")

// ---------------- fp32 -> (hi,lo) fp16 split ----------------
__global__ void cvt_split(const float* __restrict__ src, h16_t* __restrict__ hi,
                          h16_t* __restrict__ lo, int n4) {
  int i = blockIdx.x * blockDim.x + threadIdx.x;
  if (i < n4) {
    float4 v = reinterpret_cast<const float4*>(src)[i];
    half4v h, l;
    float x;
    x = v.x; h[0] = (h16_t)x; l[0] = (h16_t)(x - (float)h[0]);
    x = v.y; h[1] = (h16_t)x; l[1] = (h16_t)(x - (float)h[1]);
    x = v.z; h[2] = (h16_t)x; l[2] = (h16_t)(x - (float)h[2]);
    x = v.w; h[3] = (h16_t)x; l[3] = (h16_t)(x - (float)h[3]);
    reinterpret_cast<half4v*>(hi)[i] = h;
    reinterpret_cast<half4v*>(lo)[i] = l;
  }
}

// ---------------- fp32 W[K][N] -> fp16 Wt[N][K] hi (+ lo for n < Nlo) -------
__global__ void transpose_split(const float* __restrict__ W, h16_t* __restrict__ Wt_hi,
                                h16_t* __restrict__ Wt_lo, int K, int N, int Nlo) {
  __shared__ float tile[32][33];
  int n0 = blockIdx.x * 32, k0 = blockIdx.y * 32;
  int tx = threadIdx.x, ty = threadIdx.y;  // 32 x 8
#pragma unroll
  for (int j = 0; j < 4; ++j)
    tile[ty + 8 * j][tx] = W[(size_t)(k0 + ty + 8 * j) * N + n0 + tx];
  __syncthreads();
  bool do_lo = (Wt_lo != nullptr) && (n0 < Nlo);
#pragma unroll
  for (int j = 0; j < 4; ++j) {
    float v = tile[tx][ty + 8 * j];
    h16_t hv = (h16_t)v;
    size_t off = (size_t)(n0 + ty + 8 * j) * K + k0 + tx;
    Wt_hi[off] = hv;
    if (do_lo) Wt_lo[off] = (h16_t)(v - (float)hv);
  }
}

// ---------------- fp16 V columns of qkv -> Vt[vc][s] ----------------
__global__ void vtrans_kernel(const h16_t* __restrict__ qkv_hi, h16_t* __restrict__ vt) {
  __shared__ h16_t tile[32][33];
  int vc0 = blockIdx.x * 32, s0 = blockIdx.y * 32;
  int tx = threadIdx.x, ty = threadIdx.y;  // 32 x 8
#pragma unroll
  for (int j = 0; j < 4; ++j)
    tile[ty + 8 * j][tx] = qkv_hi[(size_t)(s0 + ty + 8 * j) * QKVW + 4096 + vc0 + tx];
  __syncthreads();
#pragma unroll
  for (int j = 0; j < 4; ++j)
    vt[(size_t)(vc0 + ty + 8 * j) * SEQ + s0 + tx] = tile[tx][ty + 8 * j];
}

// ---------------- GEMM: C[M][N] = A[M][K] * Bt[N][K]^T + bias ----------------
// 128x128 tile, BK=32, 4 waves (2x2). global_load_lds double-buffered 2-phase.
// SPLIT: 3-product Markidis. OUT: 0 = fp16 hi, 1 = fp16 hi+lo, 2 = fp32.
template <int SPLIT, int OUT>
__global__ __launch_bounds__(256) void gemm_f16(
    const h16_t* __restrict__ Ahi, const h16_t* __restrict__ Alo,
    const h16_t* __restrict__ Bhi, const h16_t* __restrict__ Blo,
    const float* __restrict__ bias, void* __restrict__ Cout,
    h16_t* __restrict__ Clo, int ldc, int K, int ldlo) {
  constexpr int BUF = SPLIT ? 32768 : 16384;
  __shared__ __align__(16) char smem[2 * BUF];

  const int tid = threadIdx.x;
  const int w = tid >> 6, lane = tid & 63, c = lane & 15, g = lane >> 4;
  const int brow = blockIdx.y * 128, bcol = blockIdx.x * 128;
  const int wr = (w >> 1) * 64, wc = (w & 1) * 64;

  f32x4 acc[4][4] = {};

  // stage K-step k0 into buffer bufi (linear dest, inverse-swizzled source)
  auto stage = [&](int bufi, int k0) {
    char* buf = smem + bufi * BUF;
#pragma unroll
    for (int it = 0; it < 2; ++it) {
      int B = it * 256 + tid;
      int row = B >> 2;
      int c8 = (B & 3) ^ ((row >> 1) & 3);
      int loff = it * 4096 + w * 1024;
      GLOAD_LDS(Ahi + (size_t)(brow + row) * K + k0 + c8 * 8, buf + loff);
      GLOAD_LDS(Bhi + (size_t)(bcol + row) * K + k0 + c8 * 8, buf + 8192 + loff);
      if (SPLIT) {
        GLOAD_LDS(Alo + (size_t)(brow + row) * K + k0 + c8 * 8, buf + 16384 + loff);
        GLOAD_LDS(Blo + (size_t)(bcol + row) * K + k0 + c8 * 8, buf + 24576 + loff);
      }
    }
  };

  int cur = 0;
  stage(0, 0);
  VMCNT0;
  __syncthreads();

  for (int k0 = 0; k0 < K; k0 += 32) {
    if (k0 + 32 < K) stage(cur ^ 1, k0 + 32);
    const char* bufc = smem + cur * BUF;
    half8 afh[4], bfh[4], afl[4], bfl[4];
#pragma unroll
    for (int f = 0; f < 4; ++f) {
      int rowa = wr + f * 16 + c;
      int offa = rowa * 64 + ((g ^ ((rowa >> 1) & 3)) * 16);
      int rowb = wc + f * 16 + c;
      int offb = rowb * 64 + ((g ^ ((rowb >> 1) & 3)) * 16);
      afh[f] = *reinterpret_cast<const half8*>(bufc + offa);
      bfh[f] = *reinterpret_cast<const half8*>(bufc + 8192 + offb);
      if (SPLIT) {
        afl[f] = *reinterpret_cast<const half8*>(bufc + 16384 + offa);
        bfl[f] = *reinterpret_cast<const half8*>(bufc + 24576 + offb);
      }
    }
#pragma unroll
    for (int fm = 0; fm < 4; ++fm)
#pragma unroll
      for (int fn = 0; fn < 4; ++fn) {
        acc[fm][fn] = __builtin_amdgcn_mfma_f32_16x16x32_f16(afh[fm], bfh[fn], acc[fm][fn], 0, 0, 0);
        if (SPLIT) {
          acc[fm][fn] = __builtin_amdgcn_mfma_f32_16x16x32_f16(afh[fm], bfl[fn], acc[fm][fn], 0, 0, 0);
          acc[fm][fn] = __builtin_amdgcn_mfma_f32_16x16x32_f16(afl[fm], bfh[fn], acc[fm][fn], 0, 0, 0);
        }
      }
    VMCNT0;
    __syncthreads();
    cur ^= 1;
  }

#pragma unroll
  for (int fm = 0; fm < 4; ++fm)
#pragma unroll
    for (int fn = 0; fn < 4; ++fn) {
      int col = bcol + wc + fn * 16 + c;
      float bv = bias[col];
#pragma unroll
      for (int r = 0; r < 4; ++r) {
        int row = brow + wr + fm * 16 + 4 * g + r;
        float v = acc[fm][fn][r] + bv;
        if (OUT == 2) {
          ((float*)Cout)[(size_t)row * ldc + col] = v;
        } else {
          h16_t hv = (h16_t)v;
          ((h16_t*)Cout)[(size_t)row * ldc + col] = hv;
          if (OUT == 1) Clo[(size_t)row * ldlo + col] = (h16_t)(v - (float)hv);
        }
      }
    }
}

// ---------------- cos/sin table [SEQ][64] fp32 ----------------
__global__ void ctab_kernel(float2* __restrict__ tab) {
  int idx = blockIdx.x * blockDim.x + threadIdx.x;  // 2048*64
  int s = idx >> 6, i = idx & 63;
  float freq = 1.0f / powf(10000.0f, (float)(2 * i) / 128.0f);
  float ang = (float)s * freq;
  float sn, cs;
  sincosf(ang, &sn, &cs);
  tab[idx] = make_float2(cs, sn);
}

// ---------------- RoPE (interleaved pairs), in-place on split q,k ----------
__global__ void rope_kernel(h16_t* __restrict__ hi, h16_t* __restrict__ lo,
                            const float2* __restrict__ tab) {
  int idx = blockIdx.x * blockDim.x + threadIdx.x;  // 2048*2*16*64
  int i = idx & 63;
  int hh = (idx >> 6) & 15;
  int part = (idx >> 10) & 1;
  int s = idx >> 11;
  float2 cc = tab[s * 64 + i];
  size_t offh = (size_t)s * QKVW + part * 2048 + hh * 128 + 2 * i;
  size_t offl = (size_t)s * 4096 + part * 2048 + hh * 128 + 2 * i;
  float x0 = (float)hi[offh] + (float)lo[offl];
  float x1 = (float)hi[offh + 1] + (float)lo[offl + 1];
  float y0 = x0 * cc.x - x1 * cc.y;
  float y1 = x0 * cc.y + x1 * cc.x;
  h16_t h0 = (h16_t)y0, h1 = (h16_t)y1;
  hi[offh] = h0;     lo[offl] = (h16_t)(y0 - (float)h0);
  hi[offh + 1] = h1; lo[offl + 1] = (h16_t)(y1 - (float)h1);
}

// ---------------- causal flash attention (split q,k logits) ----------------
// grid (16 pairs, 16 heads), 256 thr = 4 waves, 16 q-rows/wave (QB=64).
// Block processes qblocks (i, 31-i) sequentially: uniform 66 KVBLK=32 steps.
// Staging: global_load_lds dbuf {Khi 8K | Klo 8K | Vt 8K} x2 = 48KB LDS.
__global__ __launch_bounds__(256) void attn_kernel(const h16_t* __restrict__ qhi,
                                                   const h16_t* __restrict__ qlo,
                                                   const h16_t* __restrict__ vt,
                                                   h16_t* __restrict__ ctx) {
  __shared__ __align__(16) char smem[49152];
  const int tid = threadIdx.x, w = tid >> 6, lane = tid & 63, c = lane & 15, g = lane >> 4;
  const int h = blockIdx.y;
  const h16_t* Kph = qhi + 2048 + h * HDIM;
  const h16_t* Kpl = qlo + 2048 + h * HDIM;
  const h16_t* Vth = vt + (size_t)h * HDIM * SEQ;
  const float L2E = 1.4426950408889634f;

  // stage one KVBLK=32 tile (Khi, Klo row-major swizzled; Vt [128 d][32 key])
  auto stage = [&](int bufi, int k0) {
    char* buf = smem + bufi * 24576;
#pragma unroll
    for (int it = 0; it < 2; ++it) {
      int B = it * 256 + tid;
      int loff = it * 4096 + w * 1024;
      int row = B >> 4;                       // key row 0..31
      int c16 = (B & 15) ^ (row & 7);
      GLOAD_LDS(Kph + (size_t)(k0 + row) * QKVW + c16 * 8, buf + loff);
      GLOAD_LDS(Kpl + (size_t)(k0 + row) * 4096 + c16 * 8, buf + 8192 + loff);
      int rv = B >> 2;                        // d row 0..127
      int c4 = (B & 3) ^ ((rv >> 1) & 3);
      GLOAD_LDS(Vth + (size_t)rv * SEQ + k0 + c4 * 8, buf + 16384 + loff);
    }
  };

  int cur = 0;
  const int qbA = blockIdx.x;  // 0..15

#pragma unroll 1
  for (int ph = 0; ph < 2; ++ph) {
    const int qb = ph ? (31 - qbA) : qbA;
    const int q0 = qb * 64;
    const int qw = q0 + w * 16;
    const int ntiles = (q0 >> 5) + 2;

    half8 qfh[4], qfl[4];
#pragma unroll
    for (int kc = 0; kc < 4; ++kc) {
      qfh[kc] = *reinterpret_cast<const half8*>(qhi + (size_t)(qw + c) * QKVW + h * HDIM + kc * 32 + g * 8);
      qfl[kc] = *reinterpret_cast<const half8*>(qlo + (size_t)(qw + c) * 4096 + h * HDIM + kc * 32 + g * 8);
    }

    f32x4 oacc[8] = {};
    float m_run = -3.0e38f, s_run = 0.f;

    stage(cur, 0);
    VMCNT0;
    __syncthreads();

#pragma unroll 1
    for (int t = 0; t < ntiles; ++t) {
      const int k0 = t * 32;
      if (t + 1 < ntiles) stage(cur ^ 1, k0 + 32);
      const char* buf = smem + cur * 24576;
      const char* bufV = buf + 16384;

      // S^T = K * Q, 3-product split (32 keys x 16 q per wave)
      f32x4 st[2] = {};
#pragma unroll
      for (int kc = 0; kc < 4; ++kc)
#pragma unroll
        for (int fm = 0; fm < 2; ++fm) {
          int row = fm * 16 + c;
          int so = row * 256 + (((4 * kc + g) ^ (row & 7)) * 16);
          half8 kfh = *reinterpret_cast<const half8*>(buf + so);
          half8 kfl = *reinterpret_cast<const half8*>(buf + 8192 + so);
          st[fm] = __builtin_amdgcn_mfma_f32_16x16x32_f16(kfh, qfh[kc], st[fm], 0, 0, 0);
          st[fm] = __builtin_amdgcn_mfma_f32_16x16x32_f16(kfh, qfl[kc], st[fm], 0, 0, 0);
          st[fm] = __builtin_amdgcn_mfma_f32_16x16x32_f16(kfl, qfh[kc], st[fm], 0, 0, 0);
        }

      // scale + causal mask + online softmax
      float p_[2][4];
      float tmax = -3.0e38f;
      const int qg = qw + c;
#pragma unroll
      for (int fm = 0; fm < 2; ++fm)
#pragma unroll
        for (int r = 0; r < 4; ++r) {
          float sf = st[fm][r] * 11.31370850f;  // * sqrt(128), per reference
          int key = k0 + fm * 16 + 4 * g + r;
          sf = (key > qg) ? -3.0e38f : sf;
          p_[fm][r] = sf;
          tmax = fmaxf(tmax, sf);
        }
      tmax = fmaxf(tmax, __shfl_xor(tmax, 16));
      tmax = fmaxf(tmax, __shfl_xor(tmax, 32));
      float m_new = fmaxf(m_run, tmax);
      float alpha = exp2f((m_run - m_new) * L2E);
      float rs = 0.f;
#pragma unroll
      for (int fm = 0; fm < 2; ++fm)
#pragma unroll
        for (int r = 0; r < 4; ++r) {
          float e = exp2f((p_[fm][r] - m_new) * L2E);
          p_[fm][r] = e;
          rs += e;
        }
      rs += __shfl_xor(rs, 16);
      rs += __shfl_xor(rs, 32);
      s_run = s_run * alpha + rs;
      m_run = m_new;

      float ar[4];
#pragma unroll
      for (int r = 0; r < 4; ++r) ar[r] = __shfl(alpha, 4 * g + r);
#pragma unroll
      for (int tt = 0; tt < 8; ++tt)
#pragma unroll
        for (int r = 0; r < 4; ++r) oacc[tt][r] *= ar[r];

      // pack P fragment: slot i <-> key 16*(i>>2) + 4g + (i&3)  (per-lane, free)
      half8 ap;
#pragma unroll
      for (int i = 0; i < 8; ++i) ap[i] = (h16_t)p_[i >> 2][i & 3];

      // PV: B-frag = two swizzled b64 reads of Vt (keys 4g..4g+3, 16+4g..16+4g+3)
#pragma unroll
      for (int tt = 0; tt < 8; ++tt) {
        int row = 16 * tt + c;
        int sw = (row >> 1) & 3;
        int b1 = (g >> 1), b2 = 2 + (g >> 1);
        int a1 = row * 64 + (((b1 ^ sw)) * 16) + 8 * (g & 1);
        int a2 = row * 64 + (((b2 ^ sw)) * 16) + 8 * (g & 1);
        union { half8 v8; half4v v4[2]; } u;
        u.v4[0] = *reinterpret_cast<const half4v*>(bufV + a1);
        u.v4[1] = *reinterpret_cast<const half4v*>(bufV + a2);
        oacc[tt] = __builtin_amdgcn_mfma_f32_16x16x32_f16(ap, u.v8, oacc[tt], 0, 0, 0);
      }

      VMCNT0;
      __syncthreads();
      cur ^= 1;
    }

    float sr[4];
#pragma unroll
    for (int r = 0; r < 4; ++r) sr[r] = __shfl(s_run, 4 * g + r);
#pragma unroll
    for (int tt = 0; tt < 8; ++tt)
#pragma unroll
      for (int r = 0; r < 4; ++r) {
        float v = oacc[tt][r] / sr[r];
        ctx[(size_t)(qw + 4 * g + r) * DM + h * HDIM + tt * 16 + c] = (h16_t)v;
      }
  }
}

extern "C" void kernel_launch(void* const* d_in, const int* in_sizes, int n_in,
                              void* d_out, int out_size, void* d_ws, size_t ws_size,
                              hipStream_t stream) {
  const float* hs   = (const float*)d_in[0];
  const float* wqkv = (const float*)d_in[1];
  const float* bqkv = (const float*)d_in[2];
  const float* wo   = (const float*)d_in[3];
  const float* bo   = (const float*)d_in[4];
  float* out = (float*)d_out;

  char* ws = (char*)d_ws;
  const size_t MB = 1u << 20;
  h16_t* h_hi    = (h16_t*)(ws + 0 * MB);    // 8 MB  (reused as ctx16 later)
  h16_t* h_lo    = (h16_t*)(ws + 8 * MB);    // 8 MB
  h16_t* qkvT_hi = (h16_t*)(ws + 16 * MB);   // 24 MB [6144][2048]
  h16_t* qkvT_lo = (h16_t*)(ws + 40 * MB);   // 16 MB [4096][2048]
  h16_t* woT     = (h16_t*)(ws + 56 * MB);   // 8 MB  [2048][2048]
  h16_t* qkv_hi  = (h16_t*)(ws + 64 * MB);   // 24 MB [2048][6144]
  h16_t* qkv_lo  = (h16_t*)(ws + 88 * MB);   // 16 MB [2048][4096]
  float2* ctab   = (float2*)(ws + 104 * MB); // 1 MB  [2048][64]
  h16_t* vt      = (h16_t*)(ws + 105 * MB);  // 8 MB  [2048 vc][2048 s]
  h16_t* ctx16   = h_hi;

  cvt_split<<<(SEQ * DM / 4 + 255) / 256, 256, 0, stream>>>(hs, h_hi, h_lo, SEQ * DM / 4);
  transpose_split<<<dim3(QKVW / 32, DM / 32), dim3(32, 8), 0, stream>>>(
      wqkv, qkvT_hi, qkvT_lo, DM, QKVW, 4096);
  transpose_split<<<dim3(DM / 32, DM / 32), dim3(32, 8), 0, stream>>>(
      wo, woT, nullptr, DM, DM, 0);
  ctab_kernel<<<(SEQ * 64) / 256, 256, 0, stream>>>(ctab);

  // q,k columns: split 3-product GEMM, writes hi+lo
  gemm_f16<1, 1><<<dim3(32, 16), 256, 0, stream>>>(
      h_hi, h_lo, qkvT_hi, qkvT_lo, bqkv, qkv_hi, qkv_lo, QKVW, DM, 4096);
  // v columns: plain GEMM, hi only
  gemm_f16<0, 0><<<dim3(16, 16), 256, 0, stream>>>(
      h_hi, nullptr, qkvT_hi + (size_t)4096 * DM, nullptr, bqkv + 4096,
      qkv_hi + 4096, nullptr, QKVW, DM, 0);

  vtrans_kernel<<<dim3(DM / 32, SEQ / 32), dim3(32, 8), 0, stream>>>(qkv_hi, vt);
  rope_kernel<<<(SEQ * 2 * NHEAD * 64) / 256, 256, 0, stream>>>(qkv_hi, qkv_lo, ctab);

  attn_kernel<<<dim3(16, 16), 256, 0, stream>>>(qkv_hi, qkv_lo, vt, ctx16);

  gemm_f16<0, 2><<<dim3(DM / 128, SEQ / 128), 256, 0, stream>>>(
      ctx16, nullptr, woT, nullptr, bo, out, nullptr, DM, DM, 0);
}

// Round 4
// 316.862 us; speedup vs baseline: 1.3747x; 1.0030x over previous
//
#include <hip/hip_runtime.h>

typedef _Float16 h16_t;
typedef _Float16 half8 __attribute__((ext_vector_type(8)));
typedef _Float16 half4v __attribute__((ext_vector_type(4)));
typedef float f32x4 __attribute__((ext_vector_type(4)));

#define SEQ 2048
#define DM 2048
#define NHEAD 16
#define HDIM 128
#define QKVW 6144

#define GLOAD_LDS(g, l)                                                   \
  __builtin_amdgcn_global_load_lds(                                       \
      (const __attribute__((address_space(1))) void*)(g),                 \
      (__attribute__((address_space(3))) void*)(l), 16, 0, 0)

#define VMCNT0 asm volatile("s_waitcnt vmcnt(0)" ::: "memory")

// ---------------- fp32 -> (hi,lo) fp16 split ----------------
__global__ void cvt_split(const float* __restrict__ src, h16_t* __restrict__ hi,
                          h16_t* __restrict__ lo, int n4) {
  int i = blockIdx.x * blockDim.x + threadIdx.x;
  if (i < n4) {
    float4 v = reinterpret_cast<const float4*>(src)[i];
    half4v h, l;
    float x;
    x = v.x; h[0] = (h16_t)x; l[0] = (h16_t)(x - (float)h[0]);
    x = v.y; h[1] = (h16_t)x; l[1] = (h16_t)(x - (float)h[1]);
    x = v.z; h[2] = (h16_t)x; l[2] = (h16_t)(x - (float)h[2]);
    x = v.w; h[3] = (h16_t)x; l[3] = (h16_t)(x - (float)h[3]);
    reinterpret_cast<half4v*>(hi)[i] = h;
    reinterpret_cast<half4v*>(lo)[i] = l;
  }
}

// ---------------- fp32 W[K][N] -> fp16 Wt[N][K] hi (+ lo for n < Nlo) -------
__global__ void transpose_split(const float* __restrict__ W, h16_t* __restrict__ Wt_hi,
                                h16_t* __restrict__ Wt_lo, int K, int N, int Nlo) {
  __shared__ float tile[32][33];
  int n0 = blockIdx.x * 32, k0 = blockIdx.y * 32;
  int tx = threadIdx.x, ty = threadIdx.y;  // 32 x 8
#pragma unroll
  for (int j = 0; j < 4; ++j)
    tile[ty + 8 * j][tx] = W[(size_t)(k0 + ty + 8 * j) * N + n0 + tx];
  __syncthreads();
  bool do_lo = (Wt_lo != nullptr) && (n0 < Nlo);
#pragma unroll
  for (int j = 0; j < 4; ++j) {
    float v = tile[tx][ty + 8 * j];
    h16_t hv = (h16_t)v;
    size_t off = (size_t)(n0 + ty + 8 * j) * K + k0 + tx;
    Wt_hi[off] = hv;
    if (do_lo) Wt_lo[off] = (h16_t)(v - (float)hv);
  }
}

// ---------------- fp16 V columns of qkv -> Vt[vc][s] ----------------
__global__ void vtrans_kernel(const h16_t* __restrict__ qkv_hi, h16_t* __restrict__ vt) {
  __shared__ h16_t tile[32][33];
  int vc0 = blockIdx.x * 32, s0 = blockIdx.y * 32;
  int tx = threadIdx.x, ty = threadIdx.y;  // 32 x 8
#pragma unroll
  for (int j = 0; j < 4; ++j)
    tile[ty + 8 * j][tx] = qkv_hi[(size_t)(s0 + ty + 8 * j) * QKVW + 4096 + vc0 + tx];
  __syncthreads();
#pragma unroll
  for (int j = 0; j < 4; ++j)
    vt[(size_t)(vc0 + ty + 8 * j) * SEQ + s0 + tx] = tile[tx][ty + 8 * j];
}

// ---------------- GEMM: C[M][N] = A[M][K] * Bt[N][K]^T + bias ----------------
// 128x128 tile, BK=32, 4 waves (2x2). global_load_lds double-buffered 2-phase.
// SPLIT: 3-product Markidis. OUT: 0 = fp16 hi, 1 = fp16 hi+lo, 2 = fp32.
template <int SPLIT, int OUT>
__global__ __launch_bounds__(256) void gemm_f16(
    const h16_t* __restrict__ Ahi, const h16_t* __restrict__ Alo,
    const h16_t* __restrict__ Bhi, const h16_t* __restrict__ Blo,
    const float* __restrict__ bias, void* __restrict__ Cout,
    h16_t* __restrict__ Clo, int ldc, int K, int ldlo) {
  constexpr int BUF = SPLIT ? 32768 : 16384;
  __shared__ __align__(16) char smem[2 * BUF];

  const int tid = threadIdx.x;
  const int w = tid >> 6, lane = tid & 63, c = lane & 15, g = lane >> 4;
  const int brow = blockIdx.y * 128, bcol = blockIdx.x * 128;
  const int wr = (w >> 1) * 64, wc = (w & 1) * 64;

  f32x4 acc[4][4] = {};

  // stage K-step k0 into buffer bufi (linear dest, inverse-swizzled source)
  auto stage = [&](int bufi, int k0) {
    char* buf = smem + bufi * BUF;
#pragma unroll
    for (int it = 0; it < 2; ++it) {
      int B = it * 256 + tid;
      int row = B >> 2;
      int c8 = (B & 3) ^ ((row >> 1) & 3);
      int loff = it * 4096 + w * 1024;
      GLOAD_LDS(Ahi + (size_t)(brow + row) * K + k0 + c8 * 8, buf + loff);
      GLOAD_LDS(Bhi + (size_t)(bcol + row) * K + k0 + c8 * 8, buf + 8192 + loff);
      if (SPLIT) {
        GLOAD_LDS(Alo + (size_t)(brow + row) * K + k0 + c8 * 8, buf + 16384 + loff);
        GLOAD_LDS(Blo + (size_t)(bcol + row) * K + k0 + c8 * 8, buf + 24576 + loff);
      }
    }
  };

  int cur = 0;
  stage(0, 0);
  VMCNT0;
  __syncthreads();

  for (int k0 = 0; k0 < K; k0 += 32) {
    if (k0 + 32 < K) stage(cur ^ 1, k0 + 32);
    const char* bufc = smem + cur * BUF;
    half8 afh[4], bfh[4], afl[4], bfl[4];
#pragma unroll
    for (int f = 0; f < 4; ++f) {
      int rowa = wr + f * 16 + c;
      int offa = rowa * 64 + ((g ^ ((rowa >> 1) & 3)) * 16);
      int rowb = wc + f * 16 + c;
      int offb = rowb * 64 + ((g ^ ((rowb >> 1) & 3)) * 16);
      afh[f] = *reinterpret_cast<const half8*>(bufc + offa);
      bfh[f] = *reinterpret_cast<const half8*>(bufc + 8192 + offb);
      if (SPLIT) {
        afl[f] = *reinterpret_cast<const half8*>(bufc + 16384 + offa);
        bfl[f] = *reinterpret_cast<const half8*>(bufc + 24576 + offb);
      }
    }
#pragma unroll
    for (int fm = 0; fm < 4; ++fm)
#pragma unroll
      for (int fn = 0; fn < 4; ++fn) {
        acc[fm][fn] = __builtin_amdgcn_mfma_f32_16x16x32_f16(afh[fm], bfh[fn], acc[fm][fn], 0, 0, 0);
        if (SPLIT) {
          acc[fm][fn] = __builtin_amdgcn_mfma_f32_16x16x32_f16(afh[fm], bfl[fn], acc[fm][fn], 0, 0, 0);
          acc[fm][fn] = __builtin_amdgcn_mfma_f32_16x16x32_f16(afl[fm], bfh[fn], acc[fm][fn], 0, 0, 0);
        }
      }
    VMCNT0;
    __syncthreads();
    cur ^= 1;
  }

#pragma unroll
  for (int fm = 0; fm < 4; ++fm)
#pragma unroll
    for (int fn = 0; fn < 4; ++fn) {
      int col = bcol + wc + fn * 16 + c;
      float bv = bias[col];
#pragma unroll
      for (int r = 0; r < 4; ++r) {
        int row = brow + wr + fm * 16 + 4 * g + r;
        float v = acc[fm][fn][r] + bv;
        if (OUT == 2) {
          ((float*)Cout)[(size_t)row * ldc + col] = v;
        } else {
          h16_t hv = (h16_t)v;
          ((h16_t*)Cout)[(size_t)row * ldc + col] = hv;
          if (OUT == 1) Clo[(size_t)row * ldlo + col] = (h16_t)(v - (float)hv);
        }
      }
    }
}

// ---------------- cos/sin table [SEQ][64] fp32 ----------------
__global__ void ctab_kernel(float2* __restrict__ tab) {
  int idx = blockIdx.x * blockDim.x + threadIdx.x;  // 2048*64
  int s = idx >> 6, i = idx & 63;
  float freq = 1.0f / powf(10000.0f, (float)(2 * i) / 128.0f);
  float ang = (float)s * freq;
  float sn, cs;
  sincosf(ang, &sn, &cs);
  tab[idx] = make_float2(cs, sn);
}

// ---------------- RoPE (interleaved pairs), in-place on split q,k ----------
__global__ void rope_kernel(h16_t* __restrict__ hi, h16_t* __restrict__ lo,
                            const float2* __restrict__ tab) {
  int idx = blockIdx.x * blockDim.x + threadIdx.x;  // 2048*2*16*64
  int i = idx & 63;
  int hh = (idx >> 6) & 15;
  int part = (idx >> 10) & 1;
  int s = idx >> 11;
  float2 cc = tab[s * 64 + i];
  size_t offh = (size_t)s * QKVW + part * 2048 + hh * 128 + 2 * i;
  size_t offl = (size_t)s * 4096 + part * 2048 + hh * 128 + 2 * i;
  float x0 = (float)hi[offh] + (float)lo[offl];
  float x1 = (float)hi[offh + 1] + (float)lo[offl + 1];
  float y0 = x0 * cc.x - x1 * cc.y;
  float y1 = x0 * cc.y + x1 * cc.x;
  h16_t h0 = (h16_t)y0, h1 = (h16_t)y1;
  hi[offh] = h0;     lo[offl] = (h16_t)(y0 - (float)h0);
  hi[offh + 1] = h1; lo[offl + 1] = (h16_t)(y1 - (float)h1);
}

// ---------------- causal flash attention (split q,k logits) ----------------
// 512 blocks, 1D. h = p&15, qb = 31-(p>>4): all blocks of head h land on
// XCD h%8 (p%16==h => p%8==h%8); per-XCD L2 working set = 2 heads = 3 MB.
// Descending qb (big blocks dispatch first) -> backfill load balance;
// 2 blocks/CU (48KB LDS) -> 2 waves/SIMD overlap.
__global__ __launch_bounds__(256) void attn_kernel(const h16_t* __restrict__ qhi,
                                                   const h16_t* __restrict__ qlo,
                                                   const h16_t* __restrict__ vt,
                                                   h16_t* __restrict__ ctx) {
  __shared__ __align__(16) char smem[49152];
  const int tid = threadIdx.x, w = tid >> 6, lane = tid & 63, c = lane & 15, g = lane >> 4;
  const int p = blockIdx.x;
  const int h = p & 15;
  const int qb = 31 - (p >> 4);
  const h16_t* Kph = qhi + 2048 + h * HDIM;
  const h16_t* Kpl = qlo + 2048 + h * HDIM;
  const h16_t* Vth = vt + (size_t)h * HDIM * SEQ;
  const float L2E = 1.4426950408889634f;

  const int q0 = qb * 64;
  const int qw = q0 + w * 16;
  const int ntiles = 2 * qb + 2;

  // stage one KVBLK=32 tile (Khi, Klo row-major swizzled; Vt [128 d][32 key])
  auto stage = [&](int bufi, int k0) {
    char* buf = smem + bufi * 24576;
#pragma unroll
    for (int it = 0; it < 2; ++it) {
      int B = it * 256 + tid;
      int loff = it * 4096 + w * 1024;
      int row = B >> 4;                       // key row 0..31
      int c16 = (B & 15) ^ (row & 7);
      GLOAD_LDS(Kph + (size_t)(k0 + row) * QKVW + c16 * 8, buf + loff);
      GLOAD_LDS(Kpl + (size_t)(k0 + row) * 4096 + c16 * 8, buf + 8192 + loff);
      int rv = B >> 2;                        // d row 0..127
      int c4 = (B & 3) ^ ((rv >> 1) & 3);
      GLOAD_LDS(Vth + (size_t)rv * SEQ + k0 + c4 * 8, buf + 16384 + loff);
    }
  };

  half8 qfh[4], qfl[4];
#pragma unroll
  for (int kc = 0; kc < 4; ++kc) {
    qfh[kc] = *reinterpret_cast<const half8*>(qhi + (size_t)(qw + c) * QKVW + h * HDIM + kc * 32 + g * 8);
    qfl[kc] = *reinterpret_cast<const half8*>(qlo + (size_t)(qw + c) * 4096 + h * HDIM + kc * 32 + g * 8);
  }

  f32x4 oacc[8] = {};
  float m_run = -3.0e38f, s_run = 0.f;

  int cur = 0;
  stage(cur, 0);
  VMCNT0;
  __syncthreads();

#pragma unroll 1
  for (int t = 0; t < ntiles; ++t) {
    const int k0 = t * 32;
    if (t + 1 < ntiles) stage(cur ^ 1, k0 + 32);
    const char* buf = smem + cur * 24576;
    const char* bufV = buf + 16384;

    // S^T = K * Q, 3-product split (32 keys x 16 q per wave)
    f32x4 st[2] = {};
    __builtin_amdgcn_s_setprio(1);
#pragma unroll
    for (int kc = 0; kc < 4; ++kc)
#pragma unroll
      for (int fm = 0; fm < 2; ++fm) {
        int row = fm * 16 + c;
        int so = row * 256 + (((4 * kc + g) ^ (row & 7)) * 16);
        half8 kfh = *reinterpret_cast<const half8*>(buf + so);
        half8 kfl = *reinterpret_cast<const half8*>(buf + 8192 + so);
        st[fm] = __builtin_amdgcn_mfma_f32_16x16x32_f16(kfh, qfh[kc], st[fm], 0, 0, 0);
        st[fm] = __builtin_amdgcn_mfma_f32_16x16x32_f16(kfh, qfl[kc], st[fm], 0, 0, 0);
        st[fm] = __builtin_amdgcn_mfma_f32_16x16x32_f16(kfl, qfh[kc], st[fm], 0, 0, 0);
      }
    __builtin_amdgcn_s_setprio(0);

    // scale + causal mask + online softmax (defer-max, THR=8)
    float p_[2][4];
    float tmax = -3.0e38f;
    const int qg = qw + c;
#pragma unroll
    for (int fm = 0; fm < 2; ++fm)
#pragma unroll
      for (int r = 0; r < 4; ++r) {
        float sf = st[fm][r] * 11.31370850f;  // * sqrt(128), per reference
        int key = k0 + fm * 16 + 4 * g + r;
        sf = (key > qg) ? -3.0e38f : sf;
        p_[fm][r] = sf;
        tmax = fmaxf(tmax, sf);
      }
    tmax = fmaxf(tmax, __shfl_xor(tmax, 16));
    tmax = fmaxf(tmax, __shfl_xor(tmax, 32));
    if (!__all(tmax - m_run <= 8.0f)) {
      float m_new = fmaxf(m_run, tmax);
      float alpha = exp2f((m_run - m_new) * L2E);
      float ar[4];
#pragma unroll
      for (int r = 0; r < 4; ++r) ar[r] = __shfl(alpha, 4 * g + r);
#pragma unroll
      for (int tt = 0; tt < 8; ++tt)
#pragma unroll
        for (int r = 0; r < 4; ++r) oacc[tt][r] *= ar[r];
      s_run *= alpha;
      m_run = m_new;
    }
    float rs = 0.f;
#pragma unroll
    for (int fm = 0; fm < 2; ++fm)
#pragma unroll
      for (int r = 0; r < 4; ++r) {
        float e = exp2f((p_[fm][r] - m_run) * L2E);
        p_[fm][r] = e;
        rs += e;
      }
    rs += __shfl_xor(rs, 16);
    rs += __shfl_xor(rs, 32);
    s_run += rs;

    // pack P fragment: slot i <-> key 16*(i>>2) + 4g + (i&3)  (per-lane, free)
    half8 ap;
#pragma unroll
    for (int i = 0; i < 8; ++i) ap[i] = (h16_t)p_[i >> 2][i & 3];

    // PV: B-frag = two swizzled b64 reads of Vt (keys 4g..4g+3, 16+4g..16+4g+3)
    __builtin_amdgcn_s_setprio(1);
#pragma unroll
    for (int tt = 0; tt < 8; ++tt) {
      int row = 16 * tt + c;
      int sw = (row >> 1) & 3;
      int b1 = (g >> 1), b2 = 2 + (g >> 1);
      int a1 = row * 64 + (((b1 ^ sw)) * 16) + 8 * (g & 1);
      int a2 = row * 64 + (((b2 ^ sw)) * 16) + 8 * (g & 1);
      union { half8 v8; half4v v4[2]; } u;
      u.v4[0] = *reinterpret_cast<const half4v*>(bufV + a1);
      u.v4[1] = *reinterpret_cast<const half4v*>(bufV + a2);
      oacc[tt] = __builtin_amdgcn_mfma_f32_16x16x32_f16(ap, u.v8, oacc[tt], 0, 0, 0);
    }
    __builtin_amdgcn_s_setprio(0);

    VMCNT0;
    __syncthreads();
    cur ^= 1;
  }

  float sr[4];
#pragma unroll
  for (int r = 0; r < 4; ++r) sr[r] = __shfl(s_run, 4 * g + r);
#pragma unroll
  for (int tt = 0; tt < 8; ++tt)
#pragma unroll
    for (int r = 0; r < 4; ++r) {
      float v = oacc[tt][r] / sr[r];
      ctx[(size_t)(qw + 4 * g + r) * DM + h * HDIM + tt * 16 + c] = (h16_t)v;
    }
}

extern "C" void kernel_launch(void* const* d_in, const int* in_sizes, int n_in,
                              void* d_out, int out_size, void* d_ws, size_t ws_size,
                              hipStream_t stream) {
  const float* hs   = (const float*)d_in[0];
  const float* wqkv = (const float*)d_in[1];
  const float* bqkv = (const float*)d_in[2];
  const float* wo   = (const float*)d_in[3];
  const float* bo   = (const float*)d_in[4];
  float* out = (float*)d_out;

  char* ws = (char*)d_ws;
  const size_t MB = 1u << 20;
  h16_t* h_hi    = (h16_t*)(ws + 0 * MB);    // 8 MB  (reused as ctx16 later)
  h16_t* h_lo    = (h16_t*)(ws + 8 * MB);    // 8 MB
  h16_t* qkvT_hi = (h16_t*)(ws + 16 * MB);   // 24 MB [6144][2048]
  h16_t* qkvT_lo = (h16_t*)(ws + 40 * MB);   // 16 MB [4096][2048]
  h16_t* woT     = (h16_t*)(ws + 56 * MB);   // 8 MB  [2048][2048]
  h16_t* qkv_hi  = (h16_t*)(ws + 64 * MB);   // 24 MB [2048][6144]
  h16_t* qkv_lo  = (h16_t*)(ws + 88 * MB);   // 16 MB [2048][4096]
  float2* ctab   = (float2*)(ws + 104 * MB); // 1 MB  [2048][64]
  h16_t* vt      = (h16_t*)(ws + 105 * MB);  // 8 MB  [2048 vc][2048 s]
  h16_t* ctx16   = h_hi;

  cvt_split<<<(SEQ * DM / 4 + 255) / 256, 256, 0, stream>>>(hs, h_hi, h_lo, SEQ * DM / 4);
  transpose_split<<<dim3(QKVW / 32, DM / 32), dim3(32, 8), 0, stream>>>(
      wqkv, qkvT_hi, qkvT_lo, DM, QKVW, 4096);
  transpose_split<<<dim3(DM / 32, DM / 32), dim3(32, 8), 0, stream>>>(
      wo, woT, nullptr, DM, DM, 0);
  ctab_kernel<<<(SEQ * 64) / 256, 256, 0, stream>>>(ctab);

  // q,k columns: split 3-product GEMM, writes hi+lo
  gemm_f16<1, 1><<<dim3(32, 16), 256, 0, stream>>>(
      h_hi, h_lo, qkvT_hi, qkvT_lo, bqkv, qkv_hi, qkv_lo, QKVW, DM, 4096);
  // v columns: plain GEMM, hi only
  gemm_f16<0, 0><<<dim3(16, 16), 256, 0, stream>>>(
      h_hi, nullptr, qkvT_hi + (size_t)4096 * DM, nullptr, bqkv + 4096,
      qkv_hi + 4096, nullptr, QKVW, DM, 0);

  vtrans_kernel<<<dim3(DM / 32, SEQ / 32), dim3(32, 8), 0, stream>>>(qkv_hi, vt);
  rope_kernel<<<(SEQ * 2 * NHEAD * 64) / 256, 256, 0, stream>>>(qkv_hi, qkv_lo, ctab);

  attn_kernel<<<512, 256, 0, stream>>>(qkv_hi, qkv_lo, vt, ctx16);

  gemm_f16<0, 2><<<dim3(DM / 128, SEQ / 128), 256, 0, stream>>>(
      ctx16, nullptr, woT, nullptr, bo, out, nullptr, DM, DM, 0);
}

// Round 5
// 298.596 us; speedup vs baseline: 1.4588x; 1.0612x over previous
//
#include <hip/hip_runtime.h>

typedef _Float16 h16_t;
typedef _Float16 half8 __attribute__((ext_vector_type(8)));
typedef _Float16 half4v __attribute__((ext_vector_type(4)));
typedef float f32x4 __attribute__((ext_vector_type(4)));

#define SEQ 2048
#define DM 2048
#define NHEAD 16
#define HDIM 128
#define QKVW 6144

#define GLOAD_LDS(g, l)                                                   \
  __builtin_amdgcn_global_load_lds(                                       \
      (const __attribute__((address_space(1))) void*)(g),                 \
      (__attribute__((address_space(3))) void*)(l), 16, 0, 0)

#define VMCNT0 asm volatile("s_waitcnt vmcnt(0)" ::: "memory")
#define VMCNT6 asm volatile("s_waitcnt vmcnt(6)" ::: "memory")

// ---------------- fp32 -> (hi,lo) fp16 split ----------------
__global__ void cvt_split(const float* __restrict__ src, h16_t* __restrict__ hi,
                          h16_t* __restrict__ lo, int n4) {
  int i = blockIdx.x * blockDim.x + threadIdx.x;
  if (i < n4) {
    float4 v = reinterpret_cast<const float4*>(src)[i];
    half4v h, l;
    float x;
    x = v.x; h[0] = (h16_t)x; l[0] = (h16_t)(x - (float)h[0]);
    x = v.y; h[1] = (h16_t)x; l[1] = (h16_t)(x - (float)h[1]);
    x = v.z; h[2] = (h16_t)x; l[2] = (h16_t)(x - (float)h[2]);
    x = v.w; h[3] = (h16_t)x; l[3] = (h16_t)(x - (float)h[3]);
    reinterpret_cast<half4v*>(hi)[i] = h;
    reinterpret_cast<half4v*>(lo)[i] = l;
  }
}

// ---------------- fp32 W[K][N] -> fp16 Wt[N][K] hi (+ lo for n < Nlo) -------
__global__ void transpose_split(const float* __restrict__ W, h16_t* __restrict__ Wt_hi,
                                h16_t* __restrict__ Wt_lo, int K, int N, int Nlo) {
  __shared__ float tile[32][33];
  int n0 = blockIdx.x * 32, k0 = blockIdx.y * 32;
  int tx = threadIdx.x, ty = threadIdx.y;  // 32 x 8
#pragma unroll
  for (int j = 0; j < 4; ++j)
    tile[ty + 8 * j][tx] = W[(size_t)(k0 + ty + 8 * j) * N + n0 + tx];
  __syncthreads();
  bool do_lo = (Wt_lo != nullptr) && (n0 < Nlo);
#pragma unroll
  for (int j = 0; j < 4; ++j) {
    float v = tile[tx][ty + 8 * j];
    h16_t hv = (h16_t)v;
    size_t off = (size_t)(n0 + ty + 8 * j) * K + k0 + tx;
    Wt_hi[off] = hv;
    if (do_lo) Wt_lo[off] = (h16_t)(v - (float)hv);
  }
}

// ---------------- fp16 V columns of qkv -> Vt[vc][s] ----------------
__global__ void vtrans_kernel(const h16_t* __restrict__ qkv_hi, h16_t* __restrict__ vt) {
  __shared__ h16_t tile[32][33];
  int vc0 = blockIdx.x * 32, s0 = blockIdx.y * 32;
  int tx = threadIdx.x, ty = threadIdx.y;  // 32 x 8
#pragma unroll
  for (int j = 0; j < 4; ++j)
    tile[ty + 8 * j][tx] = qkv_hi[(size_t)(s0 + ty + 8 * j) * QKVW + 4096 + vc0 + tx];
  __syncthreads();
#pragma unroll
  for (int j = 0; j < 4; ++j)
    vt[(size_t)(vc0 + ty + 8 * j) * SEQ + s0 + tx] = tile[tx][ty + 8 * j];
}

// ---------------- GEMM: C[M][N] = A[M][K] * Bt[N][K]^T + bias ----------------
// 128x128 tile, BK=32, 4 waves (2x2). global_load_lds double-buffered 2-phase.
// SPLIT: 3-product Markidis. OUT: 0 = fp16 hi, 1 = fp16 hi+lo, 2 = fp32.
template <int SPLIT, int OUT>
__global__ __launch_bounds__(256) void gemm_f16(
    const h16_t* __restrict__ Ahi, const h16_t* __restrict__ Alo,
    const h16_t* __restrict__ Bhi, const h16_t* __restrict__ Blo,
    const float* __restrict__ bias, void* __restrict__ Cout,
    h16_t* __restrict__ Clo, int ldc, int K, int ldlo) {
  constexpr int BUF = SPLIT ? 32768 : 16384;
  __shared__ __align__(16) char smem[2 * BUF];

  const int tid = threadIdx.x;
  const int w = tid >> 6, lane = tid & 63, c = lane & 15, g = lane >> 4;
  const int brow = blockIdx.y * 128, bcol = blockIdx.x * 128;
  const int wr = (w >> 1) * 64, wc = (w & 1) * 64;

  f32x4 acc[4][4] = {};

  // stage K-step k0 into buffer bufi (linear dest, inverse-swizzled source)
  auto stage = [&](int bufi, int k0) {
    char* buf = smem + bufi * BUF;
#pragma unroll
    for (int it = 0; it < 2; ++it) {
      int B = it * 256 + tid;
      int row = B >> 2;
      int c8 = (B & 3) ^ ((row >> 1) & 3);
      int loff = it * 4096 + w * 1024;
      GLOAD_LDS(Ahi + (size_t)(brow + row) * K + k0 + c8 * 8, buf + loff);
      GLOAD_LDS(Bhi + (size_t)(bcol + row) * K + k0 + c8 * 8, buf + 8192 + loff);
      if (SPLIT) {
        GLOAD_LDS(Alo + (size_t)(brow + row) * K + k0 + c8 * 8, buf + 16384 + loff);
        GLOAD_LDS(Blo + (size_t)(bcol + row) * K + k0 + c8 * 8, buf + 24576 + loff);
      }
    }
  };

  int cur = 0;
  stage(0, 0);
  VMCNT0;
  __syncthreads();

  for (int k0 = 0; k0 < K; k0 += 32) {
    if (k0 + 32 < K) stage(cur ^ 1, k0 + 32);
    const char* bufc = smem + cur * BUF;
    half8 afh[4], bfh[4], afl[4], bfl[4];
#pragma unroll
    for (int f = 0; f < 4; ++f) {
      int rowa = wr + f * 16 + c;
      int offa = rowa * 64 + ((g ^ ((rowa >> 1) & 3)) * 16);
      int rowb = wc + f * 16 + c;
      int offb = rowb * 64 + ((g ^ ((rowb >> 1) & 3)) * 16);
      afh[f] = *reinterpret_cast<const half8*>(bufc + offa);
      bfh[f] = *reinterpret_cast<const half8*>(bufc + 8192 + offb);
      if (SPLIT) {
        afl[f] = *reinterpret_cast<const half8*>(bufc + 16384 + offa);
        bfl[f] = *reinterpret_cast<const half8*>(bufc + 24576 + offb);
      }
    }
#pragma unroll
    for (int fm = 0; fm < 4; ++fm)
#pragma unroll
      for (int fn = 0; fn < 4; ++fn) {
        acc[fm][fn] = __builtin_amdgcn_mfma_f32_16x16x32_f16(afh[fm], bfh[fn], acc[fm][fn], 0, 0, 0);
        if (SPLIT) {
          acc[fm][fn] = __builtin_amdgcn_mfma_f32_16x16x32_f16(afh[fm], bfl[fn], acc[fm][fn], 0, 0, 0);
          acc[fm][fn] = __builtin_amdgcn_mfma_f32_16x16x32_f16(afl[fm], bfh[fn], acc[fm][fn], 0, 0, 0);
        }
      }
    VMCNT0;
    __syncthreads();
    cur ^= 1;
  }

#pragma unroll
  for (int fm = 0; fm < 4; ++fm)
#pragma unroll
    for (int fn = 0; fn < 4; ++fn) {
      int col = bcol + wc + fn * 16 + c;
      float bv = bias[col];
#pragma unroll
      for (int r = 0; r < 4; ++r) {
        int row = brow + wr + fm * 16 + 4 * g + r;
        float v = acc[fm][fn][r] + bv;
        if (OUT == 2) {
          ((float*)Cout)[(size_t)row * ldc + col] = v;
        } else {
          h16_t hv = (h16_t)v;
          ((h16_t*)Cout)[(size_t)row * ldc + col] = hv;
          if (OUT == 1) Clo[(size_t)row * ldlo + col] = (h16_t)(v - (float)hv);
        }
      }
    }
}

// ---------------- cos/sin table [SEQ][64] fp32 ----------------
__global__ void ctab_kernel(float2* __restrict__ tab) {
  int idx = blockIdx.x * blockDim.x + threadIdx.x;  // 2048*64
  int s = idx >> 6, i = idx & 63;
  float freq = 1.0f / powf(10000.0f, (float)(2 * i) / 128.0f);
  float ang = (float)s * freq;
  float sn, cs;
  sincosf(ang, &sn, &cs);
  tab[idx] = make_float2(cs, sn);
}

// ---------------- RoPE (interleaved pairs), in-place on split q,k ----------
// Folds the reference's *sqrt(128) logit scale into q (exact fp32, commutes
// with the rotation).
__global__ void rope_kernel(h16_t* __restrict__ hi, h16_t* __restrict__ lo,
                            const float2* __restrict__ tab) {
  int idx = blockIdx.x * blockDim.x + threadIdx.x;  // 2048*2*16*64
  int i = idx & 63;
  int hh = (idx >> 6) & 15;
  int part = (idx >> 10) & 1;
  int s = idx >> 11;
  float2 cc = tab[s * 64 + i];
  float fac = part ? 1.0f : 11.31370849898476f;  // sqrt(128) folded into q
  size_t offh = (size_t)s * QKVW + part * 2048 + hh * 128 + 2 * i;
  size_t offl = (size_t)s * 4096 + part * 2048 + hh * 128 + 2 * i;
  float x0 = (float)hi[offh] + (float)lo[offl];
  float x1 = (float)hi[offh + 1] + (float)lo[offl + 1];
  float y0 = (x0 * cc.x - x1 * cc.y) * fac;
  float y1 = (x0 * cc.y + x1 * cc.x) * fac;
  h16_t h0 = (h16_t)y0, h1 = (h16_t)y1;
  hi[offh] = h0;     lo[offl] = (h16_t)(y0 - (float)h0);
  hi[offh + 1] = h1; lo[offl + 1] = (h16_t)(y1 - (float)h1);
}

// ---------------- causal flash attention, split-K + counted-vmcnt ----------
// 768 blocks: h = p&15 (XCD-pinned), cq = p>>4:
//   cq<16 : qb=16+cq, keys [0,1024)            -> partial chunk 0
//   cq<32 : qb=47-cq, keys [1024,(qb+1)*64)    -> partial chunk 1
//   else  : qb=47-cq (15..0), all keys         -> direct ctx write
// 3-buffer pipeline, ONE raw s_barrier per tile, counted vmcnt(6): stage(t)
// issued 2 tiles ahead of use -> L2 latency hidden (no vmcnt(0) drain).
__global__ __launch_bounds__(256) void attn_kernel(const h16_t* __restrict__ qhi,
                                                   const h16_t* __restrict__ qlo,
                                                   const h16_t* __restrict__ vt,
                                                   h16_t* __restrict__ ctx,
                                                   float* __restrict__ Opart,
                                                   float* __restrict__ ms) {
  __shared__ __align__(16) char smem[3 * 24576];
  const int tid = threadIdx.x, w = tid >> 6, lane = tid & 63, c = lane & 15, g = lane >> 4;
  const int p = blockIdx.x;
  const int h = p & 15;
  const int cq = p >> 4;
  int qb, t0, nt, pidx;
  if (cq < 16)      { qb = 16 + cq; t0 = 0;  nt = 32;          pidx = h * 32 + cq * 2; }
  else if (cq < 32) { qb = 47 - cq; t0 = 32; nt = 2 * qb - 30; pidx = h * 32 + (qb - 16) * 2 + 1; }
  else              { qb = 47 - cq; t0 = 0;  nt = 2 * qb + 2;  pidx = -1; }

  const h16_t* Kph = qhi + 2048 + h * HDIM;
  const h16_t* Kpl = qlo + 2048 + h * HDIM;
  const h16_t* Vth = vt + (size_t)h * HDIM * SEQ;
  const float L2E = 1.4426950408889634f;

  const int q0 = qb * 64;
  const int qw = q0 + w * 16;

  // stage one KVBLK=32 tile (Khi, Klo row-major swizzled; Vt [128 d][32 key])
  auto stage = [&](int bufi, int t) {
    char* buf = smem + bufi * 24576;
    const int k0 = t * 32;
#pragma unroll
    for (int it = 0; it < 2; ++it) {
      int B = it * 256 + tid;
      int loff = it * 4096 + w * 1024;
      int row = B >> 4;                       // key row 0..31
      int c16 = (B & 15) ^ (row & 7);
      GLOAD_LDS(Kph + (size_t)(k0 + row) * QKVW + c16 * 8, buf + loff);
      GLOAD_LDS(Kpl + (size_t)(k0 + row) * 4096 + c16 * 8, buf + 8192 + loff);
      int rv = B >> 2;                        // d row 0..127
      int c4 = (B & 3) ^ ((rv >> 1) & 3);
      GLOAD_LDS(Vth + (size_t)rv * SEQ + k0 + c4 * 8, buf + 16384 + loff);
    }
  };

  half8 qfh[4], qfl[4];
#pragma unroll
  for (int kc = 0; kc < 4; ++kc) {
    qfh[kc] = *reinterpret_cast<const half8*>(qhi + (size_t)(qw + c) * QKVW + h * HDIM + kc * 32 + g * 8);
    qfl[kc] = *reinterpret_cast<const half8*>(qlo + (size_t)(qw + c) * 4096 + h * HDIM + kc * 32 + g * 8);
  }

  f32x4 oacc[8] = {};
  float m_run = -3.0e38f, s_run = 0.f;

  stage(0, t0);
  if (nt > 1) stage(1, t0 + 1);

#pragma unroll 1
  for (int i = 0; i < nt; ++i) {
    // wait own stage(i) loads complete (6 loads of stage(i+1) may remain),
    // then raw barrier (NO compiler vmcnt(0) drain), then pin ordering.
    if (i + 1 < nt) { VMCNT6; } else { VMCNT0; }
    __builtin_amdgcn_s_barrier();
    __builtin_amdgcn_sched_barrier(0);
    if (i + 2 < nt) stage((i + 2) % 3, t0 + i + 2);

    const int k0 = (t0 + i) * 32;
    const char* buf = smem + (i % 3) * 24576;
    const char* bufV = buf + 16384;

    // S^T = K * Q, 3-product split (32 keys x 16 q per wave)
    f32x4 st[2] = {};
    __builtin_amdgcn_s_setprio(1);
#pragma unroll
    for (int kc = 0; kc < 4; ++kc)
#pragma unroll
      for (int fm = 0; fm < 2; ++fm) {
        int row = fm * 16 + c;
        int so = row * 256 + (((4 * kc + g) ^ (row & 7)) * 16);
        half8 kfh = *reinterpret_cast<const half8*>(buf + so);
        half8 kfl = *reinterpret_cast<const half8*>(buf + 8192 + so);
        st[fm] = __builtin_amdgcn_mfma_f32_16x16x32_f16(kfh, qfh[kc], st[fm], 0, 0, 0);
        st[fm] = __builtin_amdgcn_mfma_f32_16x16x32_f16(kfh, qfl[kc], st[fm], 0, 0, 0);
        st[fm] = __builtin_amdgcn_mfma_f32_16x16x32_f16(kfl, qfh[kc], st[fm], 0, 0, 0);
      }
    __builtin_amdgcn_s_setprio(0);

    // causal mask + online softmax (defer-max, THR=8; scale pre-folded into q)
    float p_[2][4];
    float tmax = -3.0e38f;
    const int qg = qw + c;
#pragma unroll
    for (int fm = 0; fm < 2; ++fm)
#pragma unroll
      for (int r = 0; r < 4; ++r) {
        float sf = st[fm][r];
        int key = k0 + fm * 16 + 4 * g + r;
        sf = (key > qg) ? -3.0e38f : sf;
        p_[fm][r] = sf;
        tmax = fmaxf(tmax, sf);
      }
    tmax = fmaxf(tmax, __shfl_xor(tmax, 16));
    tmax = fmaxf(tmax, __shfl_xor(tmax, 32));
    if (!__all(tmax - m_run <= 8.0f)) {
      float m_new = fmaxf(m_run, tmax);
      float alpha = exp2f((m_run - m_new) * L2E);
      float ar[4];
#pragma unroll
      for (int r = 0; r < 4; ++r) ar[r] = __shfl(alpha, 4 * g + r);
#pragma unroll
      for (int tt = 0; tt < 8; ++tt)
#pragma unroll
        for (int r = 0; r < 4; ++r) oacc[tt][r] *= ar[r];
      s_run *= alpha;
      m_run = m_new;
    }
    float rs = 0.f;
#pragma unroll
    for (int fm = 0; fm < 2; ++fm)
#pragma unroll
      for (int r = 0; r < 4; ++r) {
        float e = exp2f((p_[fm][r] - m_run) * L2E);
        p_[fm][r] = e;
        rs += e;
      }
    rs += __shfl_xor(rs, 16);
    rs += __shfl_xor(rs, 32);
    s_run += rs;

    // pack P fragment: slot i <-> key 16*(i>>2) + 4g + (i&3)  (per-lane, free)
    half8 ap;
#pragma unroll
    for (int j = 0; j < 8; ++j) ap[j] = (h16_t)p_[j >> 2][j & 3];

    // PV: B-frag = two swizzled b64 reads of Vt (keys 4g..4g+3, 16+4g..16+4g+3)
    __builtin_amdgcn_s_setprio(1);
#pragma unroll
    for (int tt = 0; tt < 8; ++tt) {
      int row = 16 * tt + c;
      int sw = (row >> 1) & 3;
      int b1 = (g >> 1), b2 = 2 + (g >> 1);
      int a1 = row * 64 + (((b1 ^ sw)) * 16) + 8 * (g & 1);
      int a2 = row * 64 + (((b2 ^ sw)) * 16) + 8 * (g & 1);
      union { half8 v8; half4v v4[2]; } u;
      u.v4[0] = *reinterpret_cast<const half4v*>(bufV + a1);
      u.v4[1] = *reinterpret_cast<const half4v*>(bufV + a2);
      oacc[tt] = __builtin_amdgcn_mfma_f32_16x16x32_f16(ap, u.v8, oacc[tt], 0, 0, 0);
    }
    __builtin_amdgcn_s_setprio(0);
  }

  if (pidx >= 0) {
    // partial: store fp32 O, m, s (consistent w.r.t. m_run reference point)
    float* Od = Opart + (size_t)pidx * 8192;
#pragma unroll
    for (int tt = 0; tt < 8; ++tt)
#pragma unroll
      for (int r = 0; r < 4; ++r)
        Od[(w * 16 + 4 * g + r) * 128 + tt * 16 + c] = oacc[tt][r];
    if (lane < 16) {
      ms[pidx * 128 + w * 16 + c] = m_run;
      ms[pidx * 128 + 64 + w * 16 + c] = s_run;
    }
  } else {
    float sr[4];
#pragma unroll
    for (int r = 0; r < 4; ++r) sr[r] = __shfl(s_run, 4 * g + r);
#pragma unroll
    for (int tt = 0; tt < 8; ++tt)
#pragma unroll
      for (int r = 0; r < 4; ++r) {
        float v = oacc[tt][r] / sr[r];
        ctx[(size_t)(qw + 4 * g + r) * DM + h * HDIM + tt * 16 + c] = (h16_t)v;
      }
  }
}

// ---------------- merge the 2-chunk partials (qb >= 16) ----------------
__global__ void attn_reduce(const float* __restrict__ Opart, const float* __restrict__ ms,
                            h16_t* __restrict__ ctx) {
  const float L2E = 1.4426950408889634f;
  int b = blockIdx.x;          // 256 = 16 heads x 16 qb
  int h = b & 15, qi = b >> 4; // qb = 16 + qi
  int p0 = (h * 32 + qi * 2);
  int tid = threadIdx.x;
  int row = tid >> 2, seg = (tid & 3) * 32;
  float m1 = ms[p0 * 128 + row], s1 = ms[p0 * 128 + 64 + row];
  float m2 = ms[(p0 + 1) * 128 + row], s2 = ms[(p0 + 1) * 128 + 64 + row];
  float M = fmaxf(m1, m2);
  float w1 = exp2f((m1 - M) * L2E), w2 = exp2f((m2 - M) * L2E);
  float inv = 1.0f / (s1 * w1 + s2 * w2);
  const float* O1 = Opart + (size_t)p0 * 8192 + row * 128 + seg;
  const float* O2 = O1 + 8192;
  h16_t* dst = ctx + (size_t)((16 + qi) * 64 + row) * DM + h * HDIM + seg;
#pragma unroll
  for (int j = 0; j < 32; j += 4) {
    float4 a = *reinterpret_cast<const float4*>(O1 + j);
    float4 c2 = *reinterpret_cast<const float4*>(O2 + j);
    dst[j]     = (h16_t)((a.x * w1 + c2.x * w2) * inv);
    dst[j + 1] = (h16_t)((a.y * w1 + c2.y * w2) * inv);
    dst[j + 2] = (h16_t)((a.z * w1 + c2.z * w2) * inv);
    dst[j + 3] = (h16_t)((a.w * w1 + c2.w * w2) * inv);
  }
}

extern "C" void kernel_launch(void* const* d_in, const int* in_sizes, int n_in,
                              void* d_out, int out_size, void* d_ws, size_t ws_size,
                              hipStream_t stream) {
  const float* hs   = (const float*)d_in[0];
  const float* wqkv = (const float*)d_in[1];
  const float* bqkv = (const float*)d_in[2];
  const float* wo   = (const float*)d_in[3];
  const float* bo   = (const float*)d_in[4];
  float* out = (float*)d_out;

  char* ws = (char*)d_ws;
  const size_t MB = 1u << 20;
  h16_t* h_hi    = (h16_t*)(ws + 0 * MB);    // 8 MB  (reused as ctx16 later)
  h16_t* h_lo    = (h16_t*)(ws + 8 * MB);    // 8 MB
  h16_t* qkvT_hi = (h16_t*)(ws + 16 * MB);   // 24 MB [6144][2048]
  h16_t* qkvT_lo = (h16_t*)(ws + 40 * MB);   // 16 MB [4096][2048]
  h16_t* woT     = (h16_t*)(ws + 56 * MB);   // 8 MB  [2048][2048]
  h16_t* qkv_hi  = (h16_t*)(ws + 64 * MB);   // 24 MB [2048][6144]
  h16_t* qkv_lo  = (h16_t*)(ws + 88 * MB);   // 16 MB [2048][4096]
  float2* ctab   = (float2*)(ws + 104 * MB); // 1 MB  [2048][64]
  h16_t* vt      = (h16_t*)(ws + 105 * MB);  // 8 MB  [2048 vc][2048 s]
  // attn partials reuse the weight-transpose region (consumed before attn):
  float* Opart   = (float*)(ws + 16 * MB);   // 16 MB [512][64][128] fp32
  float* msbuf   = (float*)(ws + 32 * MB);   // 256 KB [512][2][64] fp32
  h16_t* ctx16   = h_hi;

  cvt_split<<<(SEQ * DM / 4 + 255) / 256, 256, 0, stream>>>(hs, h_hi, h_lo, SEQ * DM / 4);
  transpose_split<<<dim3(QKVW / 32, DM / 32), dim3(32, 8), 0, stream>>>(
      wqkv, qkvT_hi, qkvT_lo, DM, QKVW, 4096);
  transpose_split<<<dim3(DM / 32, DM / 32), dim3(32, 8), 0, stream>>>(
      wo, woT, nullptr, DM, DM, 0);
  ctab_kernel<<<(SEQ * 64) / 256, 256, 0, stream>>>(ctab);

  // q,k columns: split 3-product GEMM, writes hi+lo
  gemm_f16<1, 1><<<dim3(32, 16), 256, 0, stream>>>(
      h_hi, h_lo, qkvT_hi, qkvT_lo, bqkv, qkv_hi, qkv_lo, QKVW, DM, 4096);
  // v columns: plain GEMM, hi only
  gemm_f16<0, 0><<<dim3(16, 16), 256, 0, stream>>>(
      h_hi, nullptr, qkvT_hi + (size_t)4096 * DM, nullptr, bqkv + 4096,
      qkv_hi + 4096, nullptr, QKVW, DM, 0);

  vtrans_kernel<<<dim3(DM / 32, SEQ / 32), dim3(32, 8), 0, stream>>>(qkv_hi, vt);
  rope_kernel<<<(SEQ * 2 * NHEAD * 64) / 256, 256, 0, stream>>>(qkv_hi, qkv_lo, ctab);

  attn_kernel<<<768, 256, 0, stream>>>(qkv_hi, qkv_lo, vt, ctx16, Opart, msbuf);
  attn_reduce<<<256, 256, 0, stream>>>(Opart, msbuf, ctx16);

  gemm_f16<0, 2><<<dim3(DM / 128, SEQ / 128), 256, 0, stream>>>(
      ctx16, nullptr, woT, nullptr, bo, out, nullptr, DM, DM, 0);
}